// Round 1
// baseline (473.082 us; speedup 1.0000x reference)
//
#include <hip/hip_runtime.h>
#include <stdint.h>

typedef unsigned short u16;
typedef __bf16 bf16x8 __attribute__((ext_vector_type(8)));
typedef float f32x4 __attribute__((ext_vector_type(4)));

#define NB    64
#define CIN   128
#define COUT  256
#define HO    28
#define HP    58      // padded 56x56 input (+1 halo each side)
#define HA    30      // padded 28x28 a1 (+1 halo each side)
#define MROW  784     // 28*28
#define MTOT  50176   // 64*28*28

// ---------------- workspace layout (bytes) ----------------
static constexpr size_t XT_BYTES = (size_t)NB*HP*HP*CIN*2;   // 55,115,776
static constexpr size_t A1_BYTES = (size_t)NB*HA*HA*COUT*2;  // 29,491,200
static constexpr size_t SC_BYTES = (size_t)MTOT*COUT*2;      // 25,690,112
static constexpr size_t B1_BYTES = (size_t)COUT*1152*2;
static constexpr size_t B2_BYTES = (size_t)COUT*2304*2;
static constexpr size_t BS_BYTES = (size_t)COUT*128*2;
static constexpr size_t OFF_XT = 0;
static constexpr size_t OFF_A1 = OFF_XT + XT_BYTES;
static constexpr size_t OFF_SC = OFF_A1 + A1_BYTES;
static constexpr size_t OFF_B1 = OFF_SC + SC_BYTES;
static constexpr size_t OFF_B2 = OFF_B1 + B1_BYTES;
static constexpr size_t OFF_BS = OFF_B2 + B2_BYTES;
static constexpr size_t OFF_BETA = OFF_BS + BS_BYTES;        // 3*256 floats

// ---------------- helpers ----------------
static __device__ __forceinline__ u16 f2bf(float f) {        // RNE f32->bf16
  uint32_t u = __float_as_uint(f);
  u += 0x7fffu + ((u >> 16) & 1u);
  return (u16)(u >> 16);
}
static __device__ __forceinline__ float bf2f(u16 v) {
  return __uint_as_float(((uint32_t)v) << 16);
}

typedef const __attribute__((address_space(1))) uint32_t* gas1;
typedef __attribute__((address_space(3))) uint32_t* las3;
// async global->LDS, 16B/lane; LDS dest is wave-uniform base + lane*16
static __device__ __forceinline__ void gl16(const void* g, void* l) {
  __builtin_amdgcn_global_load_lds((gas1)(uintptr_t)g,
                                   (las3)(uint32_t)(uintptr_t)l, 16, 0, 0);
}

// BFP-quant two values belonging to the same 32-channel group (this lane has
// channels g*32+{l15, 16+l15}); group max = pairwise max + 4-step shfl_xor
// over the 16 lanes sharing the same quad (same output rows).
static __device__ __forceinline__ void quant2(float v0, float v1, float& o0, float& o1) {
  float mx = fmaxf(v0, v1);
  mx = fmaxf(mx, __shfl_xor(mx, 1));
  mx = fmaxf(mx, __shfl_xor(mx, 2));
  mx = fmaxf(mx, __shfl_xor(mx, 4));
  mx = fmaxf(mx, __shfl_xor(mx, 8));
  mx = fmaxf(mx, 1e-12f);
  const int e = (int)(__float_as_uint(mx) >> 23) - 127;         // floor(log2(mx))
  const float scale = __uint_as_float((uint32_t)(e + 121) << 23);  // 2^(e-6)
  const float invs  = __uint_as_float((uint32_t)(133 - e) << 23);  // 2^(6-e)
  o0 = fminf(rintf(v0 * invs), 127.f) * scale;   // inputs are post-ReLU (>=0)
  o1 = fminf(rintf(v1 * invs), 127.f) * scale;
}

// ---------------- x: fp32 NCHW -> bf16 padded NHWC ----------------
__global__ void k_transpose(const float* __restrict__ x, u16* __restrict__ xt) {
  __shared__ float s[32][33];
  const int ht = blockIdx.x, ct = blockIdx.y, n = blockIdx.z;
  const int t = threadIdx.x, tc = t >> 5, tw = t & 31;
  const float* src = x + ((size_t)(n*CIN + ct*32))*3136 + ht*32;
#pragma unroll
  for (int i = 0; i < 4; ++i)
    s[tc + i*8][tw] = src[(size_t)(tc + i*8)*3136 + tw];
  __syncthreads();
#pragma unroll
  for (int i = 0; i < 4; ++i) {
    const int hwl = tc + i*8;
    const int hw = ht*32 + hwl;
    const int h = hw / 56, w = hw % 56;
    xt[((size_t)(n*HP + h + 1)*HP + (w + 1))*CIN + ct*32 + tw] = f2bf(s[tw][hwl]);
  }
}

// ---------------- weight quant + BN fold + relayout ----------------
__global__ void k_prep(const float* __restrict__ w1, const float* __restrict__ w2,
                       const float* __restrict__ wsc,
                       const float* __restrict__ g1, const float* __restrict__ b1,
                       const float* __restrict__ m1, const float* __restrict__ v1,
                       const float* __restrict__ g2, const float* __restrict__ b2,
                       const float* __restrict__ m2, const float* __restrict__ v2,
                       const float* __restrict__ gs, const float* __restrict__ bs,
                       const float* __restrict__ ms, const float* __restrict__ vs,
                       u16* __restrict__ B1, u16* __restrict__ B2, u16* __restrict__ Bsg,
                       float* __restrict__ beta)
{
  const int id = blockIdx.x*256 + threadIdx.x;
  if (id < 9216) {                       // w1: (o, ib, tap) blocks of 32 in-ch
    const int o = id / 36, rem = id % 36, ib = rem / 9, t = rem % 9;
    const float inv = g1[o] / sqrtf(v1[o] + 1e-5f);
    const float* base = w1 + (size_t)(o*CIN + ib*32)*9 + t;
    float mx = 0.f;
#pragma unroll 8
    for (int j = 0; j < 32; ++j) mx = fmaxf(mx, fabsf(base[j*9]));
    const float scale = fmaxf(mx, 1e-12f) / 127.0f;
    u16* dst = B1 + (size_t)o*1152 + t*CIN + ib*32;
#pragma unroll 8
    for (int j = 0; j < 32; ++j) {
      float q = rintf(base[j*9] / scale);
      q = fminf(fmaxf(q, -128.f), 127.f);
      dst[j] = f2bf(q * scale * inv);
    }
  } else if (id < 27648) {               // w2
    const int id2 = id - 9216;
    const int o = id2 / 72, rem = id2 % 72, ib = rem / 9, t = rem % 9;
    const float inv = g2[o] / sqrtf(v2[o] + 1e-5f);
    const float* base = w2 + (size_t)(o*COUT + ib*32)*9 + t;
    float mx = 0.f;
#pragma unroll 8
    for (int j = 0; j < 32; ++j) mx = fmaxf(mx, fabsf(base[j*9]));
    const float scale = fmaxf(mx, 1e-12f) / 127.0f;
    u16* dst = B2 + (size_t)o*2304 + t*COUT + ib*32;
#pragma unroll 8
    for (int j = 0; j < 32; ++j) {
      float q = rintf(base[j*9] / scale);
      q = fminf(fmaxf(q, -128.f), 127.f);
      dst[j] = f2bf(q * scale * inv);
    }
  } else if (id < 28672) {               // ws (1x1)
    const int id3 = id - 27648;
    const int o = id3 >> 2, ib = id3 & 3;
    const float inv = gs[o] / sqrtf(vs[o] + 1e-5f);
    const float* base = wsc + (size_t)o*CIN + ib*32;
    float mx = 0.f;
#pragma unroll 8
    for (int j = 0; j < 32; ++j) mx = fmaxf(mx, fabsf(base[j]));
    const float scale = fmaxf(mx, 1e-12f) / 127.0f;
    u16* dst = Bsg + (size_t)o*CIN + ib*32;
#pragma unroll 8
    for (int j = 0; j < 32; ++j) {
      float q = rintf(base[j] / scale);
      q = fminf(fmaxf(q, -128.f), 127.f);
      dst[j] = f2bf(q * scale * inv);
    }
  } else if (id < 29440) {               // betas
    const int id4 = id - 28672;
    const int which = id4 >> 8, o = id4 & 255;
    float g, b, m, v;
    if (which == 0)      { g = g1[o]; b = b1[o]; m = m1[o]; v = v1[o]; }
    else if (which == 1) { g = g2[o]; b = b2[o]; m = m2[o]; v = v2[o]; }
    else                 { g = gs[o]; b = bs[o]; m = ms[o]; v = vs[o]; }
    beta[which*256 + o] = b - m * (g / sqrtf(v + 1e-5f));
  }
}

// ---------------- implicit-GEMM conv, 128x128 tile, 4 waves ----------------
// MODE 0: conv1 3x3 s2 (A=xt),  K=1152, epi: +beta,ReLU,BFP -> a1p (bf16 NHWC pad)
// MODE 1: conv2 3x3 s1 (A=a1p), K=2304, epi: +beta,+sc,ReLU,BFP -> out fp32 NCHW
// MODE 2: shortcut 1x1 s2 (A=xt center tap), K=128, epi: +beta -> sc bf16 [m][o]
template<int MODE>
__global__ __launch_bounds__(256, 2)
void gemm_k(const u16* __restrict__ Ag, const u16* __restrict__ Bg,
            const float* __restrict__ beta, const u16* __restrict__ scin,
            u16* __restrict__ obf, float* __restrict__ of32)
{
  // LDS layout [kchunk(8 bf16)][row][8]: frag reads land 2 lanes/bank (free),
  // and rows are exactly 16B so global_load_lds's lane*16 mapping fits.
  __shared__ __align__(16) u16 As[4][128][8];
  __shared__ __align__(16) u16 Bs[4][128][8];

  const int tid = threadIdx.x;
  const int wv  = tid >> 6;
  const int ln  = tid & 63;
  const int mtile = blockIdx.x;
  const int ntile = blockIdx.y;

  constexpr int KROW = (MODE == 0) ? 1152 : (MODE == 1) ? 2304 : 128;

  // per-lane global row base addresses (this lane stages rows ln and 64+ln,
  // 16B chunk index = wv)
  const char* aA[2];
#pragma unroll
  for (int rh = 0; rh < 2; ++rh) {
    const int m = mtile*128 + rh*64 + ln;
    const int n = m / MROW, rem = m % MROW, y = rem / HO, x = rem % HO;
    int off;
    if (MODE == 0)      off = ((n*HP + 2*y    )*HP + 2*x    )*CIN  + wv*8;
    else if (MODE == 2) off = ((n*HP + 2*y + 1)*HP + 2*x + 1)*CIN  + wv*8;
    else                off = ((n*HA + y      )*HA + x      )*COUT + wv*8;
    aA[rh] = (const char*)Ag + (size_t)off*2;
  }
  const char* aB[2];
#pragma unroll
  for (int rh = 0; rh < 2; ++rh) {
    const int o = ntile*128 + rh*64 + ln;
    aB[rh] = (const char*)Bg + ((size_t)o*KROW + wv*8)*2;
  }
  void* dA[2] = { (void*)&As[wv][0][0], (void*)&As[wv][64][0] };
  void* dB[2] = { (void*)&Bs[wv][0][0], (void*)&Bs[wv][64][0] };

  const int quad = ln >> 4, l15 = ln & 15;
  const int m_off = (wv & 1)*64, n_off = (wv >> 1)*64;
  const u16* ra[4];
  const u16* rb[4];
#pragma unroll
  for (int i = 0; i < 4; ++i) {
    ra[i] = As[quad][m_off + i*16 + l15];
    rb[i] = Bs[quad][n_off + i*16 + l15];
  }

  f32x4 acc[4][4];
#pragma unroll
  for (int i = 0; i < 4; ++i)
#pragma unroll
    for (int j = 0; j < 4; ++j)
      acc[i][j] = (f32x4){0.f, 0.f, 0.f, 0.f};

  auto kstep = [&](int ao, int bo) {
    gl16(aA[0] + ao, dA[0]);
    gl16(aA[1] + ao, dA[1]);
    gl16(aB[0] + bo, dB[0]);
    gl16(aB[1] + bo, dB[1]);
    __syncthreads();                       // drains vmcnt -> LDS ready
    bf16x8 av[4], bv[4];
#pragma unroll
    for (int i = 0; i < 4; ++i) av[i] = *(const bf16x8*)ra[i];
#pragma unroll
    for (int i = 0; i < 4; ++i) bv[i] = *(const bf16x8*)rb[i];
#pragma unroll
    for (int mi = 0; mi < 4; ++mi)
#pragma unroll
      for (int ni = 0; ni < 4; ++ni)
        acc[mi][ni] = __builtin_amdgcn_mfma_f32_16x16x32_bf16(av[mi], bv[ni], acc[mi][ni], 0, 0, 0);
    __syncthreads();                       // reads done before next overwrite
  };

  if (MODE == 2) {
#pragma unroll
    for (int c = 0; c < 4; ++c) kstep(c*64, c*64);
  } else if (MODE == 0) {
    for (int t = 0; t < 9; ++t) {
      const int ao = ((t/3)*HP + (t%3))*CIN*2;   // tap byte offset in xt
#pragma unroll
      for (int c = 0; c < 4; ++c) kstep(ao + c*64, t*256 + c*64);
    }
  } else {
    for (int t = 0; t < 9; ++t) {
      const int ao = ((t/3)*HA + (t%3))*COUT*2;  // tap byte offset in a1p
#pragma unroll
      for (int c = 0; c < 8; ++c) kstep(ao + c*64, t*512 + c*64);
    }
  }

  // -------- epilogue --------
  const int mbase = mtile*128 + m_off;
  const int cbase = ntile*128 + n_off;
  float bt[4];
#pragma unroll
  for (int ni = 0; ni < 4; ++ni) bt[ni] = beta[cbase + ni*16 + l15];

  if constexpr (MODE == 2) {
#pragma unroll
    for (int mi = 0; mi < 4; ++mi)
#pragma unroll
      for (int r = 0; r < 4; ++r) {
        const int m = mbase + mi*16 + quad*4 + r;
        u16* dst = obf + (size_t)m*COUT + cbase + l15;
#pragma unroll
        for (int ni = 0; ni < 4; ++ni)
          dst[ni*16] = f2bf(acc[mi][ni][r] + bt[ni]);
      }
  } else if constexpr (MODE == 0) {
#pragma unroll
    for (int mi = 0; mi < 4; ++mi)
#pragma unroll
      for (int r = 0; r < 4; ++r) {
        const int m = mbase + mi*16 + quad*4 + r;
        const int n = m / MROW, rem = m % MROW, y = rem / HO, x = rem % HO;
        u16* dst = obf + ((size_t)(n*HA + y + 1)*HA + (x + 1))*COUT + cbase + l15;
        float v[4];
#pragma unroll
        for (int ni = 0; ni < 4; ++ni) v[ni] = fmaxf(acc[mi][ni][r] + bt[ni], 0.f);
#pragma unroll
        for (int g = 0; g < 2; ++g) {
          float o0, o1;
          quant2(v[2*g], v[2*g+1], o0, o1);
          // q*2^(e-6) is exact in bf16 -> truncate
          dst[(2*g)*16]   = (u16)(__float_as_uint(o0) >> 16);
          dst[(2*g+1)*16] = (u16)(__float_as_uint(o1) >> 16);
        }
      }
  } else {
#pragma unroll
    for (int mi = 0; mi < 4; ++mi) {
      float ov[4][4];                       // [ni][r]
#pragma unroll
      for (int r = 0; r < 4; ++r) {
        const int m = mbase + mi*16 + quad*4 + r;
        const u16* srow = scin + (size_t)m*COUT + cbase + l15;
        float v[4];
#pragma unroll
        for (int ni = 0; ni < 4; ++ni)
          v[ni] = fmaxf(acc[mi][ni][r] + bt[ni] + bf2f(srow[ni*16]), 0.f);
#pragma unroll
        for (int g = 0; g < 2; ++g)
          quant2(v[2*g], v[2*g+1], ov[2*g][r], ov[2*g+1][r]);
      }
      const int m0 = mbase + mi*16 + quad*4;  // 4-aligned, never crosses x row
      const int n = m0 / MROW, rem = m0 % MROW, y = rem / HO, x = rem % HO;
#pragma unroll
      for (int ni = 0; ni < 4; ++ni) {
        const int c = cbase + ni*16 + l15;
        f32x4 val = { ov[ni][0], ov[ni][1], ov[ni][2], ov[ni][3] };
        *(f32x4*)(of32 + ((size_t)(n*COUT + c)*HO + y)*HO + x) = val;
      }
    }
  }
}

// ---------------- launch ----------------
extern "C" void kernel_launch(void* const* d_in, const int* in_sizes, int n_in,
                              void* d_out, int out_size, void* d_ws, size_t ws_size,
                              hipStream_t stream)
{
  (void)in_sizes; (void)n_in; (void)out_size; (void)ws_size;
  const float* x   = (const float*)d_in[0];
  const float* w1  = (const float*)d_in[1];
  const float* w2  = (const float*)d_in[2];
  const float* wsc = (const float*)d_in[3];
  const float* g1 = (const float*)d_in[4];
  const float* b1 = (const float*)d_in[5];
  const float* m1 = (const float*)d_in[6];
  const float* v1 = (const float*)d_in[7];
  const float* g2 = (const float*)d_in[8];
  const float* b2 = (const float*)d_in[9];
  const float* m2 = (const float*)d_in[10];
  const float* v2 = (const float*)d_in[11];
  const float* gs = (const float*)d_in[12];
  const float* bs = (const float*)d_in[13];
  const float* ms = (const float*)d_in[14];
  const float* vs = (const float*)d_in[15];

  char* ws = (char*)d_ws;
  u16* xt   = (u16*)(ws + OFF_XT);
  u16* a1p  = (u16*)(ws + OFF_A1);
  u16* sc   = (u16*)(ws + OFF_SC);
  u16* B1   = (u16*)(ws + OFF_B1);
  u16* B2   = (u16*)(ws + OFF_B2);
  u16* Bsg  = (u16*)(ws + OFF_BS);
  float* beta = (float*)(ws + OFF_BETA);

  hipMemsetAsync(xt, 0, XT_BYTES, stream);    // zero halos (ws is re-poisoned)
  hipMemsetAsync(a1p, 0, A1_BYTES, stream);

  k_transpose<<<dim3(98, 4, 64), 256, 0, stream>>>(x, xt);
  k_prep<<<115, 256, 0, stream>>>(w1, w2, wsc, g1, b1, m1, v1,
                                  g2, b2, m2, v2, gs, bs, ms, vs,
                                  B1, B2, Bsg, beta);
  gemm_k<0><<<dim3(392, 2), 256, 0, stream>>>(xt, B1, beta, nullptr, a1p, nullptr);
  gemm_k<2><<<dim3(392, 2), 256, 0, stream>>>(xt, Bsg, beta + 512, nullptr, sc, nullptr);
  gemm_k<1><<<dim3(392, 2), 256, 0, stream>>>(a1p, B2, beta + 256, sc, nullptr, (float*)d_out);
}

// Round 2
// 470.700 us; speedup vs baseline: 1.0051x; 1.0051x over previous
//
#include <hip/hip_runtime.h>
#include <stdint.h>

typedef unsigned short u16;
typedef __bf16 bf16x8 __attribute__((ext_vector_type(8)));
typedef float f32x4 __attribute__((ext_vector_type(4)));

#define NB    64
#define CIN   128
#define COUT  256
#define HO    28
#define HP    58      // padded 56x56 input (+1 halo each side)
#define HA    30      // padded 28x28 a1 (+1 halo each side)
#define MROW  784     // 28*28
#define MTOT  50176   // 64*28*28

// ---------------- workspace layout (bytes) ----------------
static constexpr size_t XT_BYTES = (size_t)NB*HP*HP*CIN*2;   // 55,115,776
static constexpr size_t A1_BYTES = (size_t)NB*HA*HA*COUT*2;  // 29,491,200
static constexpr size_t B1_BYTES = (size_t)COUT*1152*2;      // k = tap*128 + cin
static constexpr size_t B2_BYTES = (size_t)COUT*2432*2;      // k = tap*256 + c | 2304 + cin (shortcut)
static constexpr size_t OFF_XT = 0;
static constexpr size_t OFF_A1 = OFF_XT + XT_BYTES;
static constexpr size_t OFF_B1 = OFF_A1 + A1_BYTES;
static constexpr size_t OFF_B2 = OFF_B1 + B1_BYTES;
static constexpr size_t OFF_BETA = OFF_B2 + B2_BYTES;        // 512 floats

// ---------------- helpers ----------------
static __device__ __forceinline__ u16 f2bf(float f) {        // RNE f32->bf16
  uint32_t u = __float_as_uint(f);
  u += 0x7fffu + ((u >> 16) & 1u);
  return (u16)(u >> 16);
}

typedef const __attribute__((address_space(1))) uint32_t* gas1;
typedef __attribute__((address_space(3))) uint32_t* las3;
// async global->LDS, 16B/lane; LDS dest is wave-uniform base + lane*16
static __device__ __forceinline__ void gl16(const void* g, void* l) {
  __builtin_amdgcn_global_load_lds((gas1)(uintptr_t)g,
                                   (las3)(uint32_t)(uintptr_t)l, 16, 0, 0);
}

// BFP-quant two values of the same 32-channel group (this lane holds channels
// g*32 + {l15, 16+l15}); group max via pairwise max + 4-step shfl_xor over the
// 16 lanes of the quad.
static __device__ __forceinline__ void quant2(float v0, float v1, float& o0, float& o1) {
  float mx = fmaxf(v0, v1);
  mx = fmaxf(mx, __shfl_xor(mx, 1));
  mx = fmaxf(mx, __shfl_xor(mx, 2));
  mx = fmaxf(mx, __shfl_xor(mx, 4));
  mx = fmaxf(mx, __shfl_xor(mx, 8));
  mx = fmaxf(mx, 1e-12f);
  const int e = (int)(__float_as_uint(mx) >> 23) - 127;            // floor(log2)
  const float scale = __uint_as_float((uint32_t)(e + 121) << 23);  // 2^(e-6)
  const float invs  = __uint_as_float((uint32_t)(133 - e) << 23);  // 2^(6-e)
  o0 = fminf(rintf(v0 * invs), 127.f) * scale;   // inputs post-ReLU (>=0)
  o1 = fminf(rintf(v1 * invs), 127.f) * scale;
}

// ---------------- x: fp32 NCHW -> bf16 padded NHWC ----------------
__global__ void k_transpose(const float* __restrict__ x, u16* __restrict__ xt) {
  __shared__ float s[32][33];
  const int ht = blockIdx.x, ct = blockIdx.y, n = blockIdx.z;
  const int t = threadIdx.x, tc = t >> 5, tw = t & 31;
  const float* src = x + ((size_t)(n*CIN + ct*32))*3136 + ht*32;
#pragma unroll
  for (int i = 0; i < 4; ++i)
    s[tc + i*8][tw] = src[(size_t)(tc + i*8)*3136 + tw];
  __syncthreads();
#pragma unroll
  for (int i = 0; i < 4; ++i) {
    const int hwl = tc + i*8;
    const int hw = ht*32 + hwl;
    const int h = hw / 56, w = hw % 56;
    xt[((size_t)(n*HP + h + 1)*HP + (w + 1))*CIN + ct*32 + tw] = f2bf(s[tw][hwl]);
  }
}

// ---------------- weight quant + BN fold + relayout ----------------
__global__ void k_prep(const float* __restrict__ w1, const float* __restrict__ w2,
                       const float* __restrict__ wsc,
                       const float* __restrict__ g1, const float* __restrict__ b1,
                       const float* __restrict__ m1, const float* __restrict__ v1,
                       const float* __restrict__ g2, const float* __restrict__ b2,
                       const float* __restrict__ m2, const float* __restrict__ v2,
                       const float* __restrict__ gs, const float* __restrict__ bs,
                       const float* __restrict__ ms, const float* __restrict__ vs,
                       u16* __restrict__ B1, u16* __restrict__ B2,
                       float* __restrict__ beta)
{
  const int id = blockIdx.x*256 + threadIdx.x;
  if (id < 9216) {                       // w1: (o, ib, tap) blocks of 32 in-ch
    const int o = id / 36, rem = id % 36, ib = rem / 9, t = rem % 9;
    const float inv = g1[o] / sqrtf(v1[o] + 1e-5f);
    const float* base = w1 + (size_t)(o*CIN + ib*32)*9 + t;
    float mx = 0.f;
#pragma unroll 8
    for (int j = 0; j < 32; ++j) mx = fmaxf(mx, fabsf(base[j*9]));
    const float scale = fmaxf(mx, 1e-12f) / 127.0f;
    u16* dst = B1 + (size_t)o*1152 + t*CIN + ib*32;
#pragma unroll 8
    for (int j = 0; j < 32; ++j) {
      float q = rintf(base[j*9] / scale);
      q = fminf(fmaxf(q, -128.f), 127.f);
      dst[j] = f2bf(q * scale * inv);
    }
  } else if (id < 27648) {               // w2 -> B2[o][t*256 + c]
    const int id2 = id - 9216;
    const int o = id2 / 72, rem = id2 % 72, ib = rem / 9, t = rem % 9;
    const float inv = g2[o] / sqrtf(v2[o] + 1e-5f);
    const float* base = w2 + (size_t)(o*COUT + ib*32)*9 + t;
    float mx = 0.f;
#pragma unroll 8
    for (int j = 0; j < 32; ++j) mx = fmaxf(mx, fabsf(base[j*9]));
    const float scale = fmaxf(mx, 1e-12f) / 127.0f;
    u16* dst = B2 + (size_t)o*2432 + t*COUT + ib*32;
#pragma unroll 8
    for (int j = 0; j < 32; ++j) {
      float q = rintf(base[j*9] / scale);
      q = fminf(fmaxf(q, -128.f), 127.f);
      dst[j] = f2bf(q * scale * inv);
    }
  } else if (id < 28672) {               // ws (1x1) -> B2[o][2304 + cin]
    const int id3 = id - 27648;
    const int o = id3 >> 2, ib = id3 & 3;
    const float inv = gs[o] / sqrtf(vs[o] + 1e-5f);
    const float* base = wsc + (size_t)o*CIN + ib*32;
    float mx = 0.f;
#pragma unroll 8
    for (int j = 0; j < 32; ++j) mx = fmaxf(mx, fabsf(base[j]));
    const float scale = fmaxf(mx, 1e-12f) / 127.0f;
    u16* dst = B2 + (size_t)o*2432 + 2304 + ib*32;
#pragma unroll 8
    for (int j = 0; j < 32; ++j) {
      float q = rintf(base[j] / scale);
      q = fminf(fmaxf(q, -128.f), 127.f);
      dst[j] = f2bf(q * scale * inv);
    }
  } else if (id < 29184) {               // betas: [0..255]=bn1, [256..511]=bn2+bns
    const int id4 = id - 28672;
    const int which = id4 >> 8, o = id4 & 255;
    if (which == 0) {
      beta[o] = b1[o] - m1[o] * (g1[o] / sqrtf(v1[o] + 1e-5f));
    } else {
      beta[256 + o] = (b2[o] - m2[o] * (g2[o] / sqrtf(v2[o] + 1e-5f)))
                    + (bs[o] - ms[o] * (gs[o] / sqrtf(vs[o] + 1e-5f)));
    }
  }
}

// ---------------- implicit-GEMM conv, 128x128 tile, 4 waves, dbuf LDS ------
// MODE 0: conv1 3x3 s2 (A=xt), K=3 slabs x 384; epi: +beta,ReLU,BFP -> a1p
// MODE 1: conv2 3x3 s1 (A=a1p, K=3x768) + fused shortcut 1x1 s2 (A2=xt center,
//         K=128); epi: +betaC,ReLU,BFP -> out fp32 NCHW
template<int MODE>
__global__ __launch_bounds__(256, 2)
void gemm_k(const u16* __restrict__ Ag, const u16* __restrict__ Ag2,
            const u16* __restrict__ Bg, const float* __restrict__ beta,
            u16* __restrict__ obf, float* __restrict__ of32)
{
  // [buf][kchunk(8 bf16)][row][8]; frag reads land 2 lanes/bank (free);
  // rows are 16B so global_load_lds's lane*16 mapping fits exactly.
  __shared__ __align__(16) u16 As[2][4][128][8];
  __shared__ __align__(16) u16 Bs[2][4][128][8];

  const int tid = threadIdx.x;
  const int wv  = tid >> 6;
  const int ln  = tid & 63;
  const int ntile = blockIdx.x;     // x = ntile so paired blocks share A in L2
  const int mtile = blockIdx.y;

  constexpr int S       = (MODE == 0) ? 12 : 24;       // ksteps per row-slab
  constexpr int NKA     = 3 * S;                        // main ksteps
  constexpr int NK      = (MODE == 0) ? NKA : NKA + 4;  // + shortcut slab
  constexpr int KROW    = (MODE == 0) ? 1152 : 2432;    // B row length (elems)
  constexpr int ASTRIDE = (MODE == 0) ? HP*CIN*2 : HA*COUT*2;  // bytes/slab

  // per-lane global row bases (lane stages rows ln and 64+ln; 16B chunk = wv)
  const char* aA[2];
  const char* aA2[2] = {nullptr, nullptr};
  const char* aB[2];
#pragma unroll
  for (int rh = 0; rh < 2; ++rh) {
    const int m = mtile*128 + rh*64 + ln;
    const int n = m / MROW, rem = m % MROW, y = rem / HO, x = rem % HO;
    int off;
    if (MODE == 0) off = ((n*HP + 2*y)*HP + 2*x)*CIN  + wv*8;
    else           off = ((n*HA + y  )*HA + x  )*COUT + wv*8;
    aA[rh] = (const char*)Ag + (size_t)off*2;
    if constexpr (MODE == 1) {
      const int off2 = ((n*HP + 2*y + 1)*HP + 2*x + 1)*CIN + wv*8;
      aA2[rh] = (const char*)Ag2 + (size_t)off2*2;
    }
    const int o = ntile*128 + rh*64 + ln;
    aB[rh] = (const char*)Bg + ((size_t)o*KROW + wv*8)*2;
  }
  char* const lA = (char*)&As[0][wv][0][0];
  char* const lB = (char*)&Bs[0][wv][0][0];

  const int quad = ln >> 4, l15 = ln & 15;
  const int m_off = (wv & 1)*64, n_off = (wv >> 1)*64;
  const u16* ra[4];
  const u16* rb[4];
#pragma unroll
  for (int i = 0; i < 4; ++i) {
    ra[i] = As[0][quad][m_off + i*16 + l15];
    rb[i] = Bs[0][quad][n_off + i*16 + l15];
  }

  f32x4 acc[4][4];
#pragma unroll
  for (int i = 0; i < 4; ++i)
#pragma unroll
    for (int j = 0; j < 4; ++j)
      acc[i][j] = (f32x4){0.f, 0.f, 0.f, 0.f};

  // ---- prologue: stage kstep 0 into buf 0 ----
  gl16(aA[0], lA);
  gl16(aA[1], lA + 64*16);
  gl16(aB[0], lB);
  gl16(aB[1], lB + 64*16);
  __syncthreads();

  for (int i = 0; i < NK; ++i) {
    // prefetch kstep i+1 into the other buffer (loads stay in flight while we
    // compute; the end-of-iteration barrier's vmcnt(0) drain overlaps compute)
    if (i + 1 < NK) {
      const int nk = i + 1;
      const char *a0, *a1;
      int aoff;
      if (MODE == 1 && nk >= NKA) {
        a0 = aA2[0]; a1 = aA2[1]; aoff = (nk - NKA)*64;
      } else {
        a0 = aA[0];  a1 = aA[1];  aoff = (nk / S)*ASTRIDE + (nk % S)*64;
      }
      const int lb = (nk & 1) * 8192;       // buffer byte offset
      gl16(a0 + aoff, lA + lb);
      gl16(a1 + aoff, lA + lb + 64*16);
      gl16(aB[0] + nk*64, lB + lb);
      gl16(aB[1] + nk*64, lB + lb + 64*16);
    }
    // compute on buf i&1
    const int bsel = (i & 1) * 4096;        // u16 elements
    bf16x8 av[4], bv[4];
#pragma unroll
    for (int k = 0; k < 4; ++k) av[k] = *(const bf16x8*)(ra[k] + bsel);
#pragma unroll
    for (int k = 0; k < 4; ++k) bv[k] = *(const bf16x8*)(rb[k] + bsel);
#pragma unroll
    for (int mi = 0; mi < 4; ++mi)
#pragma unroll
      for (int ni = 0; ni < 4; ++ni)
        acc[mi][ni] = __builtin_amdgcn_mfma_f32_16x16x32_bf16(av[mi], bv[ni], acc[mi][ni], 0, 0, 0);
    if (i + 1 < NK) __syncthreads();        // drain prefetch + guard reuse
  }

  // -------- epilogue --------
  const int mbase = mtile*128 + m_off;
  const int cbase = ntile*128 + n_off;
  float bt[4];
#pragma unroll
  for (int ni = 0; ni < 4; ++ni) bt[ni] = beta[cbase + ni*16 + l15];

  if constexpr (MODE == 0) {
#pragma unroll
    for (int mi = 0; mi < 4; ++mi)
#pragma unroll
      for (int r = 0; r < 4; ++r) {
        const int m = mbase + mi*16 + quad*4 + r;
        const int n = m / MROW, rem = m % MROW, y = rem / HO, x = rem % HO;
        u16* dst = obf + ((size_t)(n*HA + y + 1)*HA + (x + 1))*COUT + cbase + l15;
        float v[4];
#pragma unroll
        for (int ni = 0; ni < 4; ++ni) v[ni] = fmaxf(acc[mi][ni][r] + bt[ni], 0.f);
#pragma unroll
        for (int g = 0; g < 2; ++g) {
          float o0, o1;
          quant2(v[2*g], v[2*g+1], o0, o1);
          // q*2^(e-6) is exact in bf16 -> truncate
          dst[(2*g)*16]   = (u16)(__float_as_uint(o0) >> 16);
          dst[(2*g+1)*16] = (u16)(__float_as_uint(o1) >> 16);
        }
      }
  } else {
#pragma unroll
    for (int mi = 0; mi < 4; ++mi) {
      float ov[4][4];                       // [ni][r]
#pragma unroll
      for (int r = 0; r < 4; ++r) {
        float v[4];
#pragma unroll
        for (int ni = 0; ni < 4; ++ni)
          v[ni] = fmaxf(acc[mi][ni][r] + bt[ni], 0.f);
#pragma unroll
        for (int g = 0; g < 2; ++g)
          quant2(v[2*g], v[2*g+1], ov[2*g][r], ov[2*g+1][r]);
      }
      const int m0 = mbase + mi*16 + quad*4;  // 4-aligned; never crosses x row
      const int n = m0 / MROW, rem = m0 % MROW, y = rem / HO, x = rem % HO;
#pragma unroll
      for (int ni = 0; ni < 4; ++ni) {
        const int c = cbase + ni*16 + l15;
        f32x4 val = { ov[ni][0], ov[ni][1], ov[ni][2], ov[ni][3] };
        *(f32x4*)(of32 + ((size_t)(n*COUT + c)*HO + y)*HO + x) = val;
      }
    }
  }
}

// ---------------- launch ----------------
extern "C" void kernel_launch(void* const* d_in, const int* in_sizes, int n_in,
                              void* d_out, int out_size, void* d_ws, size_t ws_size,
                              hipStream_t stream)
{
  (void)in_sizes; (void)n_in; (void)out_size; (void)ws_size;
  const float* x   = (const float*)d_in[0];
  const float* w1  = (const float*)d_in[1];
  const float* w2  = (const float*)d_in[2];
  const float* wsc = (const float*)d_in[3];
  const float* g1 = (const float*)d_in[4];
  const float* b1 = (const float*)d_in[5];
  const float* m1 = (const float*)d_in[6];
  const float* v1 = (const float*)d_in[7];
  const float* g2 = (const float*)d_in[8];
  const float* b2 = (const float*)d_in[9];
  const float* m2 = (const float*)d_in[10];
  const float* v2 = (const float*)d_in[11];
  const float* gs = (const float*)d_in[12];
  const float* bs = (const float*)d_in[13];
  const float* ms = (const float*)d_in[14];
  const float* vs = (const float*)d_in[15];

  char* ws = (char*)d_ws;
  u16* xt   = (u16*)(ws + OFF_XT);
  u16* a1p  = (u16*)(ws + OFF_A1);
  u16* B1   = (u16*)(ws + OFF_B1);
  u16* B2   = (u16*)(ws + OFF_B2);
  float* beta = (float*)(ws + OFF_BETA);

  hipMemsetAsync(xt, 0, XT_BYTES, stream);    // zero halos (ws is re-poisoned)
  hipMemsetAsync(a1p, 0, A1_BYTES, stream);

  k_transpose<<<dim3(98, 4, 64), 256, 0, stream>>>(x, xt);
  k_prep<<<114, 256, 0, stream>>>(w1, w2, wsc, g1, b1, m1, v1,
                                  g2, b2, m2, v2, gs, bs, ms, vs,
                                  B1, B2, beta);
  gemm_k<0><<<dim3(2, 392), 256, 0, stream>>>(xt, nullptr, B1, beta, a1p, nullptr);
  gemm_k<1><<<dim3(2, 392), 256, 0, stream>>>(a1p, xt, B2, beta + 256, nullptr, (float*)d_out);
}

// Round 3
// 448.395 us; speedup vs baseline: 1.0551x; 1.0497x over previous
//
#include <hip/hip_runtime.h>
#include <stdint.h>

typedef unsigned short u16;
typedef __bf16 bf16x8 __attribute__((ext_vector_type(8)));
typedef float f32x4 __attribute__((ext_vector_type(4)));

#define NB    64
#define CIN   128
#define COUT  256
#define HO    28
#define HP    58      // padded 56x56 input (+1 halo each side)
#define HA    30      // padded 28x28 a1 (+1 halo each side)
#define MROW  784     // 28*28
#define MTOT  50176   // 64*28*28

// ---------------- workspace layout (bytes) ----------------
static constexpr size_t XT_BYTES = (size_t)NB*HP*HP*CIN*2;   // 55,115,776
static constexpr size_t A1_BYTES = (size_t)NB*HA*HA*COUT*2;  // 29,491,200
static constexpr size_t B1_BYTES = (size_t)COUT*1152*2;      // k = tap*128 + cin
static constexpr size_t B2_BYTES = (size_t)COUT*2432*2;      // k = tap*256 + c | 2304 + cin (sc)
static constexpr size_t OFF_XT = 0;
static constexpr size_t OFF_A1 = OFF_XT + XT_BYTES;
static constexpr size_t OFF_B1 = OFF_A1 + A1_BYTES;
static constexpr size_t OFF_B2 = OFF_B1 + B1_BYTES;
static constexpr size_t OFF_BETA = OFF_B2 + B2_BYTES;        // 512 floats

// ---------------- helpers ----------------
static __device__ __forceinline__ u16 f2bf(float f) {        // RNE f32->bf16
  uint32_t u = __float_as_uint(f);
  u += 0x7fffu + ((u >> 16) & 1u);
  return (u16)(u >> 16);
}

typedef const __attribute__((address_space(1))) uint32_t* gas1;
typedef __attribute__((address_space(3))) uint32_t* las3;
// async global->LDS, 16B/lane; LDS dest is wave-uniform base + lane*16
static __device__ __forceinline__ void gl16(const void* g, void* l) {
  __builtin_amdgcn_global_load_lds((gas1)(uintptr_t)g,
                                   (las3)(uint32_t)(uintptr_t)l, 16, 0, 0);
}

// BFP-quant two values of the same 32-channel group (this lane holds channels
// g*32 + {l15, 16+l15}); group max via pairwise max + 4-step shfl_xor over the
// 16 lanes of the quad.
static __device__ __forceinline__ void quant2(float v0, float v1, float& o0, float& o1) {
  float mx = fmaxf(v0, v1);
  mx = fmaxf(mx, __shfl_xor(mx, 1));
  mx = fmaxf(mx, __shfl_xor(mx, 2));
  mx = fmaxf(mx, __shfl_xor(mx, 4));
  mx = fmaxf(mx, __shfl_xor(mx, 8));
  mx = fmaxf(mx, 1e-12f);
  const int e = (int)(__float_as_uint(mx) >> 23) - 127;            // floor(log2)
  const float scale = __uint_as_float((uint32_t)(e + 121) << 23);  // 2^(e-6)
  const float invs  = __uint_as_float((uint32_t)(133 - e) << 23);  // 2^(6-e)
  o0 = fminf(rintf(v0 * invs), 127.f) * scale;   // inputs post-ReLU (>=0)
  o1 = fminf(rintf(v1 * invs), 127.f) * scale;
}

// ---------------- x: fp32 NCHW -> bf16 padded NHWC ----------------
__global__ void k_transpose(const float* __restrict__ x, u16* __restrict__ xt) {
  __shared__ float s[32][33];
  const int ht = blockIdx.x, ct = blockIdx.y, n = blockIdx.z;
  const int t = threadIdx.x, tc = t >> 5, tw = t & 31;
  const float* src = x + ((size_t)(n*CIN + ct*32))*3136 + ht*32;
#pragma unroll
  for (int i = 0; i < 4; ++i)
    s[tc + i*8][tw] = src[(size_t)(tc + i*8)*3136 + tw];
  __syncthreads();
#pragma unroll
  for (int i = 0; i < 4; ++i) {
    const int hwl = tc + i*8;
    const int hw = ht*32 + hwl;
    const int h = hw / 56, w = hw % 56;
    xt[((size_t)(n*HP + h + 1)*HP + (w + 1))*CIN + ct*32 + tw] = f2bf(s[tw][hwl]);
  }
}

// ---------------- weight quant + BN fold + relayout ----------------
__global__ void k_prep(const float* __restrict__ w1, const float* __restrict__ w2,
                       const float* __restrict__ wsc,
                       const float* __restrict__ g1, const float* __restrict__ b1,
                       const float* __restrict__ m1, const float* __restrict__ v1,
                       const float* __restrict__ g2, const float* __restrict__ b2,
                       const float* __restrict__ m2, const float* __restrict__ v2,
                       const float* __restrict__ gs, const float* __restrict__ bs,
                       const float* __restrict__ ms, const float* __restrict__ vs,
                       u16* __restrict__ B1, u16* __restrict__ B2,
                       float* __restrict__ beta)
{
  const int id = blockIdx.x*256 + threadIdx.x;
  if (id < 9216) {                       // w1: (o, ib, tap) blocks of 32 in-ch
    const int o = id / 36, rem = id % 36, ib = rem / 9, t = rem % 9;
    const float inv = g1[o] / sqrtf(v1[o] + 1e-5f);
    const float* base = w1 + (size_t)(o*CIN + ib*32)*9 + t;
    float mx = 0.f;
#pragma unroll 8
    for (int j = 0; j < 32; ++j) mx = fmaxf(mx, fabsf(base[j*9]));
    const float scale = fmaxf(mx, 1e-12f) / 127.0f;
    u16* dst = B1 + (size_t)o*1152 + t*CIN + ib*32;
#pragma unroll 8
    for (int j = 0; j < 32; ++j) {
      float q = rintf(base[j*9] / scale);
      q = fminf(fmaxf(q, -128.f), 127.f);
      dst[j] = f2bf(q * scale * inv);
    }
  } else if (id < 27648) {               // w2 -> B2[o][t*256 + c]
    const int id2 = id - 9216;
    const int o = id2 / 72, rem = id2 % 72, ib = rem / 9, t = rem % 9;
    const float inv = g2[o] / sqrtf(v2[o] + 1e-5f);
    const float* base = w2 + (size_t)(o*COUT + ib*32)*9 + t;
    float mx = 0.f;
#pragma unroll 8
    for (int j = 0; j < 32; ++j) mx = fmaxf(mx, fabsf(base[j*9]));
    const float scale = fmaxf(mx, 1e-12f) / 127.0f;
    u16* dst = B2 + (size_t)o*2432 + t*COUT + ib*32;
#pragma unroll 8
    for (int j = 0; j < 32; ++j) {
      float q = rintf(base[j*9] / scale);
      q = fminf(fmaxf(q, -128.f), 127.f);
      dst[j] = f2bf(q * scale * inv);
    }
  } else if (id < 28672) {               // ws (1x1) -> B2[o][2304 + cin]
    const int id3 = id - 27648;
    const int o = id3 >> 2, ib = id3 & 3;
    const float inv = gs[o] / sqrtf(vs[o] + 1e-5f);
    const float* base = wsc + (size_t)o*CIN + ib*32;
    float mx = 0.f;
#pragma unroll 8
    for (int j = 0; j < 32; ++j) mx = fmaxf(mx, fabsf(base[j]));
    const float scale = fmaxf(mx, 1e-12f) / 127.0f;
    u16* dst = B2 + (size_t)o*2432 + 2304 + ib*32;
#pragma unroll 8
    for (int j = 0; j < 32; ++j) {
      float q = rintf(base[j] / scale);
      q = fminf(fmaxf(q, -128.f), 127.f);
      dst[j] = f2bf(q * scale * inv);
    }
  } else if (id < 29184) {               // betas: [0..255]=bn1, [256..511]=bn2+bns
    const int id4 = id - 28672;
    const int which = id4 >> 8, o = id4 & 255;
    if (which == 0) {
      beta[o] = b1[o] - m1[o] * (g1[o] / sqrtf(v1[o] + 1e-5f));
    } else {
      beta[256 + o] = (b2[o] - m2[o] * (g2[o] / sqrtf(v2[o] + 1e-5f)))
                    + (bs[o] - ms[o] * (gs[o] / sqrtf(vs[o] + 1e-5f)));
    }
  }
}

// ---------------- implicit-GEMM conv, 128x128 tile, 4 waves ----------------
// 3-stage LDS ring, raw s_waitcnt vmcnt(N)+s_barrier: the consume-wait at
// stage i covers only stage i's loads (issued 2 ksteps earlier) -> load
// latency overlaps 2 ksteps of MFMA instead of the vmcnt(0) barrier drain.
// MODE 0: conv1 3x3 s2 (A=xt), K=3 slabs x 384; epi: +beta,ReLU,BFP -> a1p
// MODE 1: conv2 3x3 s1 (A=a1p, K=3x768) + fused shortcut 1x1 s2 (A2=xt center,
//         K=128); epi: +betaC,ReLU,BFP -> out fp32 NCHW
template<int MODE>
__global__ __launch_bounds__(256, 3)
void gemm_k(const u16* __restrict__ Ag, const u16* __restrict__ Ag2,
            const u16* __restrict__ Bg, const float* __restrict__ beta,
            u16* __restrict__ obf, float* __restrict__ of32)
{
  // [stage][kchunk(8 bf16)][row][8]; frag reads land 2 lanes/bank (free);
  // rows are 16B so global_load_lds's lane*16 mapping fits exactly.
  __shared__ __align__(16) u16 As[3][4][128][8];
  __shared__ __align__(16) u16 Bs[3][4][128][8];

  const int tid = threadIdx.x;
  const int wv  = tid >> 6;
  const int ln  = tid & 63;
  // XCD-contiguous swizzle: blocks land on XCD b%8 (round-robin dispatch);
  // give each XCD a contiguous run of 49 mtiles, both ntiles sequential, so
  // halo rows and the A-tile re-read for ntile=1 stay in that XCD's L2.
  const int b   = blockIdx.x;
  const int xcd = b & 7, j = b >> 3;
  const int mtile = xcd * 49 + (j % 49);
  const int ntile = j / 49;

  constexpr int S       = (MODE == 0) ? 12 : 24;        // ksteps per row-slab
  constexpr int NKA     = 3 * S;                        // main ksteps
  constexpr int NK      = (MODE == 0) ? NKA : NKA + 4;  // + shortcut slab
  constexpr int KROW    = (MODE == 0) ? 1152 : 2432;    // B row length (elems)
  constexpr int ASTRIDE = (MODE == 0) ? HP*CIN*2 : HA*COUT*2;  // bytes/slab

  // per-lane global row bases (lane stages rows ln and 64+ln; 16B chunk = wv)
  const char* aA[2];
  const char* aA2[2] = {nullptr, nullptr};
  const char* aB[2];
#pragma unroll
  for (int rh = 0; rh < 2; ++rh) {
    const int m = mtile*128 + rh*64 + ln;
    const int n = m / MROW, rem = m % MROW, y = rem / HO, x = rem % HO;
    int off;
    if (MODE == 0) off = ((n*HP + 2*y)*HP + 2*x)*CIN  + wv*8;
    else           off = ((n*HA + y  )*HA + x  )*COUT + wv*8;
    aA[rh] = (const char*)Ag + (size_t)off*2;
    if constexpr (MODE == 1) {
      const int off2 = ((n*HP + 2*y + 1)*HP + 2*x + 1)*CIN + wv*8;
      aA2[rh] = (const char*)Ag2 + (size_t)off2*2;
    }
    const int o = ntile*128 + rh*64 + ln;
    aB[rh] = (const char*)Bg + ((size_t)o*KROW + wv*8)*2;
  }
  char* const lA = (char*)&As[0][wv][0][0];
  char* const lB = (char*)&Bs[0][wv][0][0];

  // issue stage nk's 4 global_load_lds into ring slot `slot`
  auto issue = [&](int nk, int slot) {
    const char *a0, *a1;
    int aoff;
    if (MODE == 1 && nk >= NKA) {
      a0 = aA2[0]; a1 = aA2[1]; aoff = (nk - NKA)*64;
    } else {
      a0 = aA[0];  a1 = aA[1];  aoff = (nk / S)*ASTRIDE + (nk % S)*64;
    }
    const int lb = slot * 8192;           // stage byte stride in As/Bs
    gl16(a0 + aoff, lA + lb);
    gl16(a1 + aoff, lA + lb + 1024);
    gl16(aB[0] + nk*64, lB + lb);
    gl16(aB[1] + nk*64, lB + lb + 1024);
  };

  const int quad = ln >> 4, l15 = ln & 15;
  const int m_off = (wv & 1)*64, n_off = (wv >> 1)*64;
  const u16* ra[4];
  const u16* rb[4];
#pragma unroll
  for (int i = 0; i < 4; ++i) {
    ra[i] = As[0][quad][m_off + i*16 + l15];
    rb[i] = Bs[0][quad][n_off + i*16 + l15];
  }

  f32x4 acc[4][4];
#pragma unroll
  for (int i = 0; i < 4; ++i)
#pragma unroll
    for (int j2 = 0; j2 < 4; ++j2)
      acc[i][j2] = (f32x4){0.f, 0.f, 0.f, 0.f};

  // ---- prologue: fill the ring ----
  issue(0, 0);
  issue(1, 1);
  issue(2, 2);

  int buf = 0;
  for (int i = 0; i < NK; ++i) {
    // wait only for the OLDEST stage's 4 loads (per-wave vmcnt), then sync.
    if (i + 2 < NK)      asm volatile("s_waitcnt vmcnt(8)" ::: "memory");
    else if (i + 1 < NK) asm volatile("s_waitcnt vmcnt(4)" ::: "memory");
    else                 asm volatile("s_waitcnt vmcnt(0)" ::: "memory");
    asm volatile("s_barrier" ::: "memory");

    const int bsel = buf * 4096;          // u16 elements per stage
    bf16x8 av[4], bv[4];
#pragma unroll
    for (int k = 0; k < 4; ++k) av[k] = *(const bf16x8*)(ra[k] + bsel);
#pragma unroll
    for (int k = 0; k < 4; ++k) bv[k] = *(const bf16x8*)(rb[k] + bsel);
#pragma unroll
    for (int mi = 0; mi < 4; ++mi)
#pragma unroll
      for (int ni = 0; ni < 4; ++ni)
        acc[mi][ni] = __builtin_amdgcn_mfma_f32_16x16x32_bf16(av[mi], bv[ni], acc[mi][ni], 0, 0, 0);

    if (i + 3 < NK) {
      // all waves' ds_reads of slot `buf` retired (consumed by MFMAs above);
      // safe to overwrite after this barrier. No vmcnt drain here.
      asm volatile("s_barrier" ::: "memory");
      issue(i + 3, buf);
    }
    buf = (buf == 2) ? 0 : buf + 1;
  }

  // -------- epilogue --------
  const int mbase = mtile*128 + m_off;
  const int cbase = ntile*128 + n_off;
  float bt[4];
#pragma unroll
  for (int ni = 0; ni < 4; ++ni) bt[ni] = beta[cbase + ni*16 + l15];

  if constexpr (MODE == 0) {
#pragma unroll
    for (int mi = 0; mi < 4; ++mi)
#pragma unroll
      for (int r = 0; r < 4; ++r) {
        const int m = mbase + mi*16 + quad*4 + r;
        const int n = m / MROW, rem = m % MROW, y = rem / HO, x = rem % HO;
        u16* dst = obf + ((size_t)(n*HA + y + 1)*HA + (x + 1))*COUT + cbase + l15;
        float v[4];
#pragma unroll
        for (int ni = 0; ni < 4; ++ni) v[ni] = fmaxf(acc[mi][ni][r] + bt[ni], 0.f);
#pragma unroll
        for (int g = 0; g < 2; ++g) {
          float o0, o1;
          quant2(v[2*g], v[2*g+1], o0, o1);
          // q*2^(e-6) is exact in bf16 -> truncate
          dst[(2*g)*16]   = (u16)(__float_as_uint(o0) >> 16);
          dst[(2*g+1)*16] = (u16)(__float_as_uint(o1) >> 16);
        }
      }
  } else {
#pragma unroll
    for (int mi = 0; mi < 4; ++mi) {
      float ov[4][4];                       // [ni][r]
#pragma unroll
      for (int r = 0; r < 4; ++r) {
        float v[4];
#pragma unroll
        for (int ni = 0; ni < 4; ++ni)
          v[ni] = fmaxf(acc[mi][ni][r] + bt[ni], 0.f);
#pragma unroll
        for (int g = 0; g < 2; ++g)
          quant2(v[2*g], v[2*g+1], ov[2*g][r], ov[2*g+1][r]);
      }
      const int m0 = mbase + mi*16 + quad*4;  // 4-aligned; never crosses x row
      const int n = m0 / MROW, rem = m0 % MROW, y = rem / HO, x = rem % HO;
#pragma unroll
      for (int ni = 0; ni < 4; ++ni) {
        const int c = cbase + ni*16 + l15;
        f32x4 val = { ov[ni][0], ov[ni][1], ov[ni][2], ov[ni][3] };
        *(f32x4*)(of32 + ((size_t)(n*COUT + c)*HO + y)*HO + x) = val;
      }
    }
  }
}

// ---------------- launch ----------------
extern "C" void kernel_launch(void* const* d_in, const int* in_sizes, int n_in,
                              void* d_out, int out_size, void* d_ws, size_t ws_size,
                              hipStream_t stream)
{
  (void)in_sizes; (void)n_in; (void)out_size; (void)ws_size;
  const float* x   = (const float*)d_in[0];
  const float* w1  = (const float*)d_in[1];
  const float* w2  = (const float*)d_in[2];
  const float* wsc = (const float*)d_in[3];
  const float* g1 = (const float*)d_in[4];
  const float* b1 = (const float*)d_in[5];
  const float* m1 = (const float*)d_in[6];
  const float* v1 = (const float*)d_in[7];
  const float* g2 = (const float*)d_in[8];
  const float* b2 = (const float*)d_in[9];
  const float* m2 = (const float*)d_in[10];
  const float* v2 = (const float*)d_in[11];
  const float* gs = (const float*)d_in[12];
  const float* bs = (const float*)d_in[13];
  const float* ms = (const float*)d_in[14];
  const float* vs = (const float*)d_in[15];

  char* ws = (char*)d_ws;
  u16* xt   = (u16*)(ws + OFF_XT);
  u16* a1p  = (u16*)(ws + OFF_A1);
  u16* B1   = (u16*)(ws + OFF_B1);
  u16* B2   = (u16*)(ws + OFF_B2);
  float* beta = (float*)(ws + OFF_BETA);

  hipMemsetAsync(xt, 0, XT_BYTES, stream);    // zero halos (ws is re-poisoned)
  hipMemsetAsync(a1p, 0, A1_BYTES, stream);

  k_transpose<<<dim3(98, 4, 64), 256, 0, stream>>>(x, xt);
  k_prep<<<114, 256, 0, stream>>>(w1, w2, wsc, g1, b1, m1, v1,
                                  g2, b2, m2, v2, gs, bs, ms, vs,
                                  B1, B2, beta);
  gemm_k<0><<<784, 256, 0, stream>>>(xt, nullptr, B1, beta, a1p, nullptr);
  gemm_k<1><<<784, 256, 0, stream>>>(a1p, xt, B2, beta + 256, nullptr, (float*)d_out);
}

// Round 4
// 366.540 us; speedup vs baseline: 1.2907x; 1.2233x over previous
//
#include <hip/hip_runtime.h>
#include <stdint.h>

typedef unsigned short u16;
typedef __bf16 bf16x8 __attribute__((ext_vector_type(8)));
typedef float f32x4 __attribute__((ext_vector_type(4)));

#define NB    64
#define CIN   128
#define COUT  256
// position grid: 32 cols x 28 rows (+2 halo rows) per image; p = y*32 + x.
// cols 28..31 are garbage lanes (outputs discarded); image stride 960.
#define PIMG  960
#define MPT   7      // mtiles per image (28*32/128)
#define NMT   448    // total mtiles (64*7)

// ---------------- workspace layout ----------------
// xt4: [sub4 = (py&1)*2+(px&1)][g16][n][960][8]  space-to-depth of padded 58x58 x
// a1c: [g32][n][960][8]                           conv2 input, halo ring zero
// Bt1: [nt2][kc144][128][8]   kc = tap*16 + cin/8
// Bt2: [nt2][kc304][128][8]   kc = tap*32 + c/8 ; 288..303 = shortcut cin/8
static constexpr size_t XT4_BYTES = (size_t)64*64*PIMG*8*2;   // 62,914,560
static constexpr size_t A1C_BYTES = (size_t)32*64*PIMG*8*2;   // 31,457,280
static constexpr size_t BT1_BYTES = (size_t)2*144*128*8*2;    //    589,824
static constexpr size_t BT2_BYTES = (size_t)2*304*128*8*2;    //  1,245,184
static constexpr size_t OFF_XT4  = 0;
static constexpr size_t OFF_A1C  = OFF_XT4 + XT4_BYTES;
static constexpr size_t OFF_B1   = OFF_A1C + A1C_BYTES;
static constexpr size_t OFF_B2   = OFF_B1 + BT1_BYTES;
static constexpr size_t OFF_BETA = OFF_B2 + BT2_BYTES;        // 512 floats

// ---------------- helpers ----------------
static __device__ __forceinline__ u16 f2bf(float f) {        // RNE f32->bf16
  uint32_t u = __float_as_uint(f);
  u += 0x7fffu + ((u >> 16) & 1u);
  return (u16)(u >> 16);
}

typedef const __attribute__((address_space(1))) uint32_t* gas1;
typedef __attribute__((address_space(3))) uint32_t* las3;
// async global->LDS, 16B/lane; LDS dest = wave-uniform base + lane*16
static __device__ __forceinline__ void gl16(const void* g, void* l) {
  __builtin_amdgcn_global_load_lds((gas1)(uintptr_t)g,
                                   (las3)(uint32_t)(uintptr_t)l, 16, 0, 0);
}

// BFP-quant two values of the same 32-channel group (this lane holds channels
// g*32 + {l15, 16+l15}); group max via pairwise max + 4-step shfl_xor over the
// 16 lanes of the quad (all share one output row -> predicate is uniform).
static __device__ __forceinline__ void quant2(float v0, float v1, float& o0, float& o1) {
  float mx = fmaxf(v0, v1);
  mx = fmaxf(mx, __shfl_xor(mx, 1));
  mx = fmaxf(mx, __shfl_xor(mx, 2));
  mx = fmaxf(mx, __shfl_xor(mx, 4));
  mx = fmaxf(mx, __shfl_xor(mx, 8));
  mx = fmaxf(mx, 1e-12f);
  const int e = (int)(__float_as_uint(mx) >> 23) - 127;            // floor(log2)
  const float scale = __uint_as_float((uint32_t)(e + 121) << 23);  // 2^(e-6)
  const float invs  = __uint_as_float((uint32_t)(133 - e) << 23);  // 2^(6-e)
  o0 = fminf(rintf(v0 * invs), 127.f) * scale;   // inputs post-ReLU (>=0)
  o1 = fminf(rintf(v1 * invs), 127.f) * scale;
}

// ---------------- x: fp32 NCHW -> xt4 space-to-depth bf16 ----------------
__global__ void k_transpose(const float* __restrict__ x, u16* __restrict__ xt4) {
  __shared__ float s[32][33];
  const int ht = blockIdx.x, ct = blockIdx.y, n = blockIdx.z;
  const int t = threadIdx.x, tc = t >> 5, tw = t & 31;
  const float* src = x + ((size_t)(n*CIN + ct*32))*3136 + ht*32;
#pragma unroll
  for (int i = 0; i < 4; ++i)
    s[tc + i*8][tw] = src[(size_t)(tc + i*8)*3136 + tw];
  __syncthreads();
  const int c = ct*32 + tw;
#pragma unroll
  for (int i = 0; i < 4; ++i) {
    const int hwl = tc + i*8;
    const int hw = ht*32 + hwl;
    const int h = hw / 56, w = hw % 56;
    const int py = h + 1, px = w + 1;                 // padded coords 1..56
    const int sub = (py & 1)*2 + (px & 1);
    const int p = (py >> 1)*32 + (px >> 1);
    xt4[(((size_t)(sub*16 + (c >> 3))*64 + n)*PIMG + p)*8 + (c & 7)]
        = f2bf(s[tw][hwl]);
  }
}

// ---------------- weight quant + BN fold + pre-tile to LDS order ----------
__global__ void k_prep(const float* __restrict__ w1, const float* __restrict__ w2,
                       const float* __restrict__ wsc,
                       const float* __restrict__ g1, const float* __restrict__ b1,
                       const float* __restrict__ m1, const float* __restrict__ v1,
                       const float* __restrict__ g2, const float* __restrict__ b2,
                       const float* __restrict__ m2, const float* __restrict__ v2,
                       const float* __restrict__ gs, const float* __restrict__ bs,
                       const float* __restrict__ ms, const float* __restrict__ vs,
                       u16* __restrict__ B1, u16* __restrict__ B2,
                       float* __restrict__ beta)
{
  const int id = blockIdx.x*256 + threadIdx.x;
  if (id < 9216) {                       // w1: (o, ib, tap) blocks of 32 in-ch
    const int o = id / 36, rem = id % 36, ib = rem / 9, t = rem % 9;
    const float inv = g1[o] / sqrtf(v1[o] + 1e-5f);
    const float* base = w1 + (size_t)(o*CIN + ib*32)*9 + t;
    float mx = 0.f;
#pragma unroll 8
    for (int jj = 0; jj < 32; ++jj) mx = fmaxf(mx, fabsf(base[jj*9]));
    const float scale = fmaxf(mx, 1e-12f) / 127.0f;
#pragma unroll 8
    for (int jj = 0; jj < 32; ++jj) {
      float q = rintf(base[jj*9] / scale);
      q = fminf(fmaxf(q, -128.f), 127.f);
      const int kc = t*16 + ib*4 + (jj >> 3);
      B1[(((size_t)(o >> 7)*144 + kc)*128 + (o & 127))*8 + (jj & 7)]
          = f2bf(q * scale * inv);
    }
  } else if (id < 27648) {               // w2 -> Bt2 kc = t*32 + c/8
    const int id2 = id - 9216;
    const int o = id2 / 72, rem = id2 % 72, ib = rem / 9, t = rem % 9;
    const float inv = g2[o] / sqrtf(v2[o] + 1e-5f);
    const float* base = w2 + (size_t)(o*COUT + ib*32)*9 + t;
    float mx = 0.f;
#pragma unroll 8
    for (int jj = 0; jj < 32; ++jj) mx = fmaxf(mx, fabsf(base[jj*9]));
    const float scale = fmaxf(mx, 1e-12f) / 127.0f;
#pragma unroll 8
    for (int jj = 0; jj < 32; ++jj) {
      float q = rintf(base[jj*9] / scale);
      q = fminf(fmaxf(q, -128.f), 127.f);
      const int kc = t*32 + ib*4 + (jj >> 3);
      B2[(((size_t)(o >> 7)*304 + kc)*128 + (o & 127))*8 + (jj & 7)]
          = f2bf(q * scale * inv);
    }
  } else if (id < 28672) {               // ws (1x1) -> Bt2 kc = 288 + cin/8
    const int id3 = id - 27648;
    const int o = id3 >> 2, ib = id3 & 3;
    const float inv = gs[o] / sqrtf(vs[o] + 1e-5f);
    const float* base = wsc + (size_t)o*CIN + ib*32;
    float mx = 0.f;
#pragma unroll 8
    for (int jj = 0; jj < 32; ++jj) mx = fmaxf(mx, fabsf(base[jj]));
    const float scale = fmaxf(mx, 1e-12f) / 127.0f;
#pragma unroll 8
    for (int jj = 0; jj < 32; ++jj) {
      float q = rintf(base[jj] / scale);
      q = fminf(fmaxf(q, -128.f), 127.f);
      const int kc = 288 + ib*4 + (jj >> 3);
      B2[(((size_t)(o >> 7)*304 + kc)*128 + (o & 127))*8 + (jj & 7)]
          = f2bf(q * scale * inv);
    }
  } else if (id < 29184) {               // betas: [0..255]=bn1, [256..511]=bn2+bns
    const int id4 = id - 28672;
    const int which = id4 >> 8, o = id4 & 255;
    if (which == 0) {
      beta[o] = b1[o] - m1[o] * (g1[o] / sqrtf(v1[o] + 1e-5f));
    } else {
      beta[256 + o] = (b2[o] - m2[o] * (g2[o] / sqrtf(v2[o] + 1e-5f)))
                    + (bs[o] - ms[o] * (gs[o] / sqrtf(vs[o] + 1e-5f)));
    }
  }
}

// ---------------- implicit-GEMM conv, 128x128 tile, 4 waves ----------------
// 3-stage LDS ring, raw vmcnt(N)+s_barrier. ALL staging loads are now
// lane-contiguous 1KB (16 cache lines/instr, was 64): A-chunks contiguous via
// the linear-position layouts, B pre-tiled to LDS order.
// MODE 0: conv1 3x3 s2 from xt4 (space-to-depth), 36 ksteps; epi -> a1c
// MODE 1: conv2 3x3 s1 from a1c (72) + shortcut 1x1 s2 from xt4 sub(1,1) (4);
//         epi: +beta,ReLU,BFP -> out fp32 NCHW
template<int MODE>
__global__ __launch_bounds__(256, 3)
void gemm_k(const u16* __restrict__ Ag, const u16* __restrict__ Ag2,
            const u16* __restrict__ Bg, const float* __restrict__ beta,
            u16* __restrict__ a1c, float* __restrict__ of32)
{
  __shared__ __align__(16) u16 As[3][4][128][8];
  __shared__ __align__(16) u16 Bs[3][4][128][8];

  const int tid = threadIdx.x;
  const int wv  = tid >> 6;
  const int ln  = tid & 63;
  // XCD-contiguous swizzle: 896 blocks = 8 xcd x 112; each XCD gets 56
  // contiguous mtiles (8 images), both ntiles sequentially -> L2 locality.
  const int b   = blockIdx.x;
  const int xcd = b & 7, j = b >> 3;
  const int mtile = xcd*56 + (j % 56);
  const int ntile = j / 56;

  constexpr int NKA = (MODE == 0) ? 36 : 72;     // main-conv ksteps
  constexpr int NK  = (MODE == 0) ? 36 : 76;     // + shortcut slab
  constexpr int NKC = (MODE == 0) ? 144 : 304;   // B kchunks per ntile
  constexpr int GSH = (MODE == 0) ? 4 : 5;       // log2(g's per tap)

  const int n  = mtile / MPT;
  const int p0 = (mtile % MPT) * 128;

  const char* const Bb = (const char*)Bg + (size_t)ntile*NKC*2048 + (size_t)ln*16;

  // issue stage nk's 4 lane-contiguous 1KB loads into ring slot `slot`
  auto issue = [&](int nk, int slot) {
    const int kc = nk*4 + wv;
    const char* a;
    if (MODE == 1 && nk >= NKA) {                // shortcut: xt4 sub(1,1)
      const int g = kc - 288;
      a = (const char*)Ag2 + (((size_t)(48 + g)*64 + n)*PIMG + p0)*16;
    } else if (MODE == 0) {
      const int t = kc >> GSH, g = kc & ((1 << GSH) - 1);
      const int dy = t / 3, dx = t - dy*3;
      const int sub = (dy & 1)*2 + (dx & 1);
      a = (const char*)Ag +
          (((size_t)(sub*16 + g)*64 + n)*PIMG + p0 + (dy >> 1)*32 + (dx >> 1))*16;
    } else {
      const int t = kc >> GSH, g = kc & ((1 << GSH) - 1);
      const int dy = t / 3, dx = t - dy*3;
      a = (const char*)Ag + (((size_t)g*64 + n)*PIMG + p0 + dy*32 + dx)*16;
    }
    a += (size_t)ln*16;
    const char* bb = Bb + (size_t)kc*2048;
    char* la = (char*)&As[slot][wv][0][0];
    char* lb = (char*)&Bs[slot][wv][0][0];
    gl16(a,        la);
    gl16(a + 1024, la + 1024);
    gl16(bb,        lb);
    gl16(bb + 1024, lb + 1024);
  };

  const int quad = ln >> 4, l15 = ln & 15;
  const int m_off = (wv & 1)*64, n_off = (wv >> 1)*64;
  const u16* ra[4];
  const u16* rb[4];
#pragma unroll
  for (int i = 0; i < 4; ++i) {
    ra[i] = As[0][quad][m_off + i*16 + l15];   // quad selects kchunk (k=quad*8)
    rb[i] = Bs[0][quad][n_off + i*16 + l15];
  }

  f32x4 acc[4][4];
#pragma unroll
  for (int i = 0; i < 4; ++i)
#pragma unroll
    for (int j2 = 0; j2 < 4; ++j2)
      acc[i][j2] = (f32x4){0.f, 0.f, 0.f, 0.f};

  // ---- prologue: fill the ring ----
  issue(0, 0);
  issue(1, 1);
  issue(2, 2);

  int buf = 0;
  for (int i = 0; i < NK; ++i) {
    // wait only the OLDEST stage's 4 loads, then sync
    if (i + 2 < NK)      asm volatile("s_waitcnt vmcnt(8)" ::: "memory");
    else if (i + 1 < NK) asm volatile("s_waitcnt vmcnt(4)" ::: "memory");
    else                 asm volatile("s_waitcnt vmcnt(0)" ::: "memory");
    asm volatile("s_barrier" ::: "memory");

    const int bsel = buf * 4096;          // u16 elements per stage
    bf16x8 av[4], bv[4];
#pragma unroll
    for (int k = 0; k < 4; ++k) av[k] = *(const bf16x8*)(ra[k] + bsel);
#pragma unroll
    for (int k = 0; k < 4; ++k) bv[k] = *(const bf16x8*)(rb[k] + bsel);
#pragma unroll
    for (int mi = 0; mi < 4; ++mi)
#pragma unroll
      for (int ni = 0; ni < 4; ++ni)
        acc[mi][ni] = __builtin_amdgcn_mfma_f32_16x16x32_bf16(av[mi], bv[ni], acc[mi][ni], 0, 0, 0);

    if (i + 3 < NK) {
      // all waves' ds_reads of slot `buf` consumed; safe to refill after sync
      asm volatile("s_barrier" ::: "memory");
      issue(i + 3, buf);
    }
    buf = (buf == 2) ? 0 : buf + 1;
  }

  // -------- epilogue --------
  const int cbase = ntile*128 + n_off;
  const int p0m   = p0 + m_off;
  float bt[4];
#pragma unroll
  for (int ni = 0; ni < 4; ++ni) bt[ni] = beta[cbase + ni*16 + l15];

  if constexpr (MODE == 0) {
#pragma unroll
    for (int mi = 0; mi < 4; ++mi)
#pragma unroll
      for (int r = 0; r < 4; ++r) {
        const int idx = p0m + mi*16 + quad*4 + r;     // p within image
        if ((idx & 31) < 28) {                         // skip garbage cols
          float v[4];
#pragma unroll
          for (int ni = 0; ni < 4; ++ni) v[ni] = fmaxf(acc[mi][ni][r] + bt[ni], 0.f);
#pragma unroll
          for (int g = 0; g < 2; ++g) {
            float o0, o1;
            quant2(v[2*g], v[2*g+1], o0, o1);
            // a1 position = idx + 33 (shift into halo frame); q*2^(e-6) exact
            const int c0 = cbase + (2*g)*16 + l15;
            const int c1 = c0 + 16;
            a1c[(((size_t)(c0 >> 3)*64 + n)*PIMG + idx + 33)*8 + (c0 & 7)]
                = (u16)(__float_as_uint(o0) >> 16);
            a1c[(((size_t)(c1 >> 3)*64 + n)*PIMG + idx + 33)*8 + (c1 & 7)]
                = (u16)(__float_as_uint(o1) >> 16);
          }
        }
      }
  } else {
#pragma unroll
    for (int mi = 0; mi < 4; ++mi) {
      float ov[4][4];                       // [ni][r]
#pragma unroll
      for (int r = 0; r < 4; ++r) {
        float v[4];
#pragma unroll
        for (int ni = 0; ni < 4; ++ni)
          v[ni] = fmaxf(acc[mi][ni][r] + bt[ni], 0.f);
#pragma unroll
        for (int g = 0; g < 2; ++g)
          quant2(v[2*g], v[2*g+1], ov[2*g][r], ov[2*g+1][r]);
      }
      const int idx0 = p0m + mi*16 + quad*4;  // 4 consecutive x, same row
      const int x0 = idx0 & 31, y = idx0 >> 5;
      if (x0 < 28) {
#pragma unroll
        for (int ni = 0; ni < 4; ++ni) {
          const int c = cbase + ni*16 + l15;
          f32x4 val = { ov[ni][0], ov[ni][1], ov[ni][2], ov[ni][3] };
          *(f32x4*)(of32 + ((size_t)(n*COUT + c)*28 + y)*28 + x0) = val;
        }
      }
    }
  }
}

// ---------------- launch ----------------
extern "C" void kernel_launch(void* const* d_in, const int* in_sizes, int n_in,
                              void* d_out, int out_size, void* d_ws, size_t ws_size,
                              hipStream_t stream)
{
  (void)in_sizes; (void)n_in; (void)out_size; (void)ws_size;
  const float* x   = (const float*)d_in[0];
  const float* w1  = (const float*)d_in[1];
  const float* w2  = (const float*)d_in[2];
  const float* wsc = (const float*)d_in[3];
  const float* g1 = (const float*)d_in[4];
  const float* b1 = (const float*)d_in[5];
  const float* m1 = (const float*)d_in[6];
  const float* v1 = (const float*)d_in[7];
  const float* g2 = (const float*)d_in[8];
  const float* b2 = (const float*)d_in[9];
  const float* m2 = (const float*)d_in[10];
  const float* v2 = (const float*)d_in[11];
  const float* gs = (const float*)d_in[12];
  const float* bs = (const float*)d_in[13];
  const float* ms = (const float*)d_in[14];
  const float* vs = (const float*)d_in[15];

  char* ws = (char*)d_ws;
  u16* xt4  = (u16*)(ws + OFF_XT4);
  u16* a1c  = (u16*)(ws + OFF_A1C);
  u16* B1   = (u16*)(ws + OFF_B1);
  u16* B2   = (u16*)(ws + OFF_B2);
  float* beta = (float*)(ws + OFF_BETA);

  // zero halos + garbage lanes in one shot (xt4 and a1c are contiguous)
  hipMemsetAsync(ws, 0, OFF_B1, stream);

  k_transpose<<<dim3(98, 4, 64), 256, 0, stream>>>(x, xt4);
  k_prep<<<114, 256, 0, stream>>>(w1, w2, wsc, g1, b1, m1, v1,
                                  g2, b2, m2, v2, gs, bs, ms, vs,
                                  B1, B2, beta);
  gemm_k<0><<<896, 256, 0, stream>>>(xt4, nullptr, B1, beta, a1c, nullptr);
  gemm_k<1><<<896, 256, 0, stream>>>(a1c, xt4, B2, beta + 256, nullptr, (float*)d_out);
}